// Round 14
// baseline (211.214 us; speedup 1.0000x reference)
//
#include <hip/hip_runtime.h>
#include <stdint.h>

// Problem constants
#define B_    8
#define S_    2048
#define HID_  1024
#define H_    16
#define DH_   64
#define M_    (B_ * S_)   // 16384 rows

using bf16x8 = __attribute__((ext_vector_type(8))) __bf16;
using bf16x4 = __attribute__((ext_vector_type(4))) __bf16;
using f32x4  = __attribute__((ext_vector_type(4))) float;
using f32x16 = __attribute__((ext_vector_type(16))) float;

__device__ __forceinline__ void gload_lds16(const void* g, void* l) {
  __builtin_amdgcn_global_load_lds(
      (const __attribute__((address_space(1))) void*)g,
      (__attribute__((address_space(3))) void*)l, 16, 0, 0);
}

// ---------------- fused prep: cast (blocks 0..2047), W-transpose (2048..5119),
// ---------------- mask (5120..5127) -- one launch instead of three ----------
__global__ __launch_bounds__(256) void prep(
    const float* __restrict__ hs, __bf16* __restrict__ hsb,
    const float* __restrict__ Wq, const float* __restrict__ Wk,
    const float* __restrict__ Wv, __bf16* __restrict__ Wt,
    const int* __restrict__ mask, float* __restrict__ validf,
    float* __restrict__ counts) {
  int bid = blockIdx.x;
  int tid = threadIdx.x;
  if (bid < 2048) {
    // cast hidden_states fp32 -> bf16, 8 elems/thread/iter
    int n8 = (B_ * S_ * HID_) / 8;
    int i = bid * 256 + tid;
    int stride = 2048 * 256;
    for (; i < n8; i += stride) {
      const float4* p = (const float4*)(hs + (size_t)i * 8);
      float4 a = p[0], c = p[1];
      bf16x8 v;
      v[0] = (__bf16)a.x; v[1] = (__bf16)a.y; v[2] = (__bf16)a.z; v[3] = (__bf16)a.w;
      v[4] = (__bf16)c.x; v[5] = (__bf16)c.y; v[6] = (__bf16)c.z; v[7] = (__bf16)c.w;
      *(bf16x8*)(hsb + (size_t)i * 8) = v;
    }
  } else if (bid < 5120) {
    // W [k][n] -> Wt [w][n][k] bf16
    __shared__ float tile[32][33];
    int idx = bid - 2048;
    int w = idx >> 10, r = idx & 1023;
    int k0 = (r & 31) * 32, n0 = (r >> 5) * 32;
    const float* W = (w == 0) ? Wq : (w == 1) ? Wk : Wv;
    int tx = tid & 31, ty = tid >> 5;
#pragma unroll
    for (int i = 0; i < 4; ++i)
      tile[ty * 4 + i][tx] = W[(size_t)(k0 + ty * 4 + i) * HID_ + n0 + tx];
    __syncthreads();
#pragma unroll
    for (int i = 0; i < 4; ++i)
      Wt[(size_t)w * HID_ * HID_ + (size_t)(n0 + ty * 4 + i) * HID_ + k0 + tx] =
          (__bf16)tile[tx][ty * 4 + i];
  } else {
    // per-row validity + per-batch count
    __shared__ float red[256];
    int b = bid - 5120;
    float cnt = 0.f;
    for (int s = tid; s < S_; s += 256) {
      float v = (mask[b * S_ + s] == 0) ? 1.f : 0.f;
      validf[b * S_ + s] = v;
      cnt += v;
    }
    red[tid] = cnt;
    __syncthreads();
    for (int off = 128; off > 0; off >>= 1) {
      if (tid < off) red[tid] += red[tid + off];
      __syncthreads();
    }
    if (tid == 0) counts[b] = red[0];
  }
}

// ============ QKV GEMM: 256x256 tile, BK=64, 8-wave, R3 pipelined K-step ====
// with 32x32x16 MFMA (vs 16x16x32): same ds_read count/pattern (24 b128/wave/
// step, 2-way-free banks), but MFMA segment 2483->2163 cyc/step (m119: 2495 vs
// 2176 TF) and half the MFMA issue slots. Schedule, staging, lgkm counts
// identical to the best-measured R3 engine (124us).
// Per wave: 128x64 out = 4 m-tiles(32) x 2 n-tiles(32); acc 8 x f32x16 = 128r.
// A frag: lane holds row=(l&31)+base, k=(l>>5)*8+j (K=16, 2 groups of 8).
// C/D: col=lane&31, row=(reg&3)+8*(reg>>2)+4*(lane>>5)  [m74/m101 verified].
__global__ __launch_bounds__(512, 2) void qkv_gemm8(
    const __bf16* __restrict__ hsb, const __bf16* __restrict__ Wt,
    const float* __restrict__ biasq, const float* __restrict__ biask,
    const float* __restrict__ biasv, const float* __restrict__ validf,
    const float* __restrict__ counts, __bf16* __restrict__ qn,
    __bf16* __restrict__ kT, __bf16* __restrict__ vT) {
  __shared__ __bf16 As[2][2][128 * 64];   // [dbuf][m-half][row*64+col]
  __shared__ __bf16 Bs[2][2][128 * 64];   // [dbuf][n-half][row*64+col]

  // XCD-aware block order: each XCD gets 8 consecutive tm x all 12 (tn,w).
  int bid = blockIdx.x;
  int swz = (bid & 7) * 96 + (bid >> 3);       // 768 % 8 == 0 -> bijective
  int tm = swz / 12;
  int tnw = swz - tm * 12;
  int tn = tnw & 3;
  int w  = tnw >> 2;

  int tid = threadIdx.x;
  int lane = tid & 63, wid = tid >> 6;
  int wr = wid >> 2, wcn = wid & 3;
  int col31 = lane & 31, hi = lane >> 5;

  int m0 = tm * 256, n0 = tn * 256;
  const __bf16* Bsrc = Wt + (size_t)w * (HID_ * HID_);

  // staging constants (512 threads stage one 128x64 half = 2 x 16B each)
  int srow = tid >> 3;                              // row 0..63 (+64 for seg 1)
  int scol = ((tid & 7) ^ (srow & 7)) << 3;         // swizzled source col (elems)
  int soff = tid * 16;                              // LDS byte offset (+8192 seg 1)

  auto stA = [&](int t_, int ah) {
    const __bf16* s0 = hsb + (size_t)(m0 + ah * 128 + srow) * HID_ + t_ * 64 + scol;
    char* d = (char*)&As[t_ & 1][ah][0] + soff;
    gload_lds16(s0, d);
    gload_lds16(s0 + (size_t)64 * HID_, d + 8192);
  };
  auto stB = [&](int t_, int bh) {
    const __bf16* s0 = Bsrc + (size_t)(n0 + bh * 128 + srow) * HID_ + t_ * 64 + scol;
    char* d = (char*)&Bs[t_ & 1][bh][0] + soff;
    gload_lds16(s0, d);
    gload_lds16(s0 + (size_t)64 * HID_, d + 8192);
  };

  // ds_read constants
  int swz8 = (lane & 7) << 4;
  int hi16 = hi << 4;                // k-group byte offset within 32B k-chunk
  int arow = wr * 64 + col31;        // + m2*32 within the 128-row half
  int brow = (wcn & 1) * 64 + col31; // + n*32
  int bsel = wcn >> 1;

  f32x16 acc[4][2] = {};             // [m-tile][n-tile], 128 VGPR
  bf16x8 fb[4], fbN[4], fa0[4], fa1[4];   // frag sets: [m2|n *2 + ki]

// RD_A: frags (m2 in 0,1) x (ki in 0,1) for (MH half, KSP k-pair)
#define RD_A(DST, BUF, MH, KSP)                                               \
  _Pragma("unroll")                                                           \
  for (int q = 0; q < 4; ++q)                                                 \
    DST[q] = *(const bf16x8*)((const char*)&As[BUF][MH][0] +                  \
                              (arow + (q >> 1) * 32) * 128 +                  \
                              ((((KSP) * 64) + (q & 1) * 32 + hi16) ^ swz8)); \
  __builtin_amdgcn_sched_barrier(0);

#define RD_B(DST, BUF, KSP)                                                   \
  _Pragma("unroll")                                                           \
  for (int q = 0; q < 4; ++q)                                                 \
    DST[q] = *(const bf16x8*)((const char*)&Bs[BUF][bsel][0] +                \
                              (brow + (q >> 1) * 32) * 128 +                  \
                              ((((KSP) * 64) + (q & 1) * 32 + hi16) ^ swz8)); \
  __builtin_amdgcn_sched_barrier(0);

// CLUSTER: 8 x mfma_32x32x16 (2 m2 x 2 n x 2 ki chained)
#define CLUSTER(ACCB, FA, FB, LG)                                             \
  asm volatile("s_waitcnt lgkmcnt(" #LG ")" ::: "memory");                    \
  __builtin_amdgcn_sched_barrier(0);                                          \
  __builtin_amdgcn_s_setprio(1);                                              \
  _Pragma("unroll")                                                           \
  for (int m2 = 0; m2 < 2; ++m2)                                              \
    _Pragma("unroll")                                                         \
    for (int n = 0; n < 2; ++n)                                               \
      _Pragma("unroll")                                                       \
      for (int ki = 0; ki < 2; ++ki)                                          \
        acc[(ACCB) + m2][n] = __builtin_amdgcn_mfma_f32_32x32x16_bf16(        \
            FA[m2 * 2 + ki], FB[n * 2 + ki], acc[(ACCB) + m2][n], 0, 0, 0);   \
  __builtin_amdgcn_s_setprio(0);                                              \
  __builtin_amdgcn_sched_barrier(0);

  // prologue: stage tile 0 into buf 0
  stA(0, 0); stA(0, 1); stB(0, 0); stB(0, 1);

#pragma unroll 2
  for (int t = 0; t < 16; ++t) {
    int buf = t & 1;
    // tile t staged (issued during t-1); all reads of t-1 complete.
    asm volatile("s_waitcnt vmcnt(0)" ::: "memory");
    __builtin_amdgcn_s_barrier();
    __builtin_amdgcn_sched_barrier(0);

    // front-loaded reads, pinned group order (12 outstanding after this):
    RD_B(fb,  buf, 0);        // G1: oldest 4
    RD_A(fa0, buf, 0, 0);     // G2
    RD_A(fa1, buf, 1, 0);     // G3
    if (t < 15) { stA(t + 1, 0); stA(t + 1, 1); }

    CLUSTER(0, fa0, fb, 4)    // needs G1,G2 (8 oldest) -> lgkm(4)

    RD_B(fbN, buf, 1);        // G4
    RD_A(fa0, buf, 0, 1);     // G5 (reuse fa0 regs)
    if (t < 15) stB(t + 1, 0);

    CLUSTER(2, fa1, fb, 8)    // needs G3 done; G4,G5 outstanding -> lgkm(8)

    RD_A(fa1, buf, 1, 1);     // G6 (reuse fa1 regs)
    if (t < 15) stB(t + 1, 1);

    CLUSTER(0, fa0, fbN, 4)   // needs G4,G5; G6 outstanding -> lgkm(4)
    CLUSTER(2, fa1, fbN, 0)   // needs G6 -> lgkm(0)
  }
#undef RD_A
#undef RD_B
#undef CLUSTER

  // ---- fused epilogue (32x32 C/D layout) ----
  const float* bias = (w == 0) ? biasq : (w == 1) ? biask : biasv;
  float bb0 = bias[n0 + wcn * 64 + col31];
  float bb1 = bias[n0 + wcn * 64 + 32 + col31];

  int batch = m0 >> 11;              // 256-row tile never crosses batch (2048 rows)
  float invcnt = 1.0f / counts[batch];
  int h = tn * 4 + wcn;              // head owned by this wave

#pragma unroll
  for (int m = 0; m < 4; ++m) {
    // rows of acc[m][*]: rowbase + (r&3) + 8*(r>>2), r = 0..15
    int rowbase = m0 + (m >> 1) * 128 + wr * 64 + (m & 1) * 32 + hi * 4;
    float vld[16], sc[16];
#pragma unroll
    for (int r = 0; r < 16; ++r)
      vld[r] = validf[rowbase + (r & 3) + 8 * (r >> 2)];
#pragma unroll
    for (int r = 0; r < 16; ++r) {
      float x0 = (acc[m][0][r] + bb0) * vld[r];
      float x1 = (acc[m][1][r] + bb1) * vld[r];
      acc[m][0][r] = x0;
      acc[m][1][r] = x1;
      float s = x0 * x0 + x1 * x1;
      // reduce over the 32-lane group (cols 0..31; xor<32 stays in-group)
      s += __shfl_xor(s, 1);
      s += __shfl_xor(s, 2);
      s += __shfl_xor(s, 4);
      s += __shfl_xor(s, 8);
      s += __shfl_xor(s, 16);
      sc[r] = (w == 2) ? vld[r] * invcnt : 1.0f / fmaxf(sqrtf(s), 1e-12f);
    }
    if (w == 0) {
#pragma unroll
      for (int n = 0; n < 2; ++n) {
        int c = n0 + wcn * 64 + n * 32 + col31;
#pragma unroll
        for (int r = 0; r < 16; ++r) {
          int row = rowbase + (r & 3) + 8 * (r >> 2);
          qn[(size_t)row * HID_ + c] = (__bf16)(acc[m][n][r] * sc[r]);
        }
      }
    } else {
      __bf16* dst = (w == 1) ? kT : vT;
#pragma unroll
      for (int n = 0; n < 2; ++n) {
        int d = n * 32 + col31;
#pragma unroll
        for (int rq = 0; rq < 4; ++rq) {
          bf16x4 pk;
#pragma unroll
          for (int j = 0; j < 4; ++j)
            pk[j] = (__bf16)(acc[m][n][rq * 4 + j] * sc[rq * 4 + j]);
          int srow2 = (rowbase + 8 * rq) & (S_ - 1);   // rows rq*8..+3 consecutive
          *(bf16x4*)(dst + (size_t)((batch * H_ + h) * DH_ + d) * S_ + srow2) = pk;
        }
      }
    }
  }
}

// ---- kv phase: vkp[half][bh][d][e] = sum_{s in half} v[s,d]*k[s,e] ----
// 256 blocks (full GPU); f32 partials, reduced inside ctx_gemm.
__global__ __launch_bounds__(256) void kv_gemm(const __bf16* __restrict__ kT,
                                               const __bf16* __restrict__ vT,
                                               float* __restrict__ vkp) {
  __shared__ __align__(16) char smem[65536];
  __bf16* kbuf = (__bf16*)smem;              // [64][256]
  __bf16* vbuf = (__bf16*)(smem + 32768);    // [64][256]

  int bh = blockIdx.x & 127, half = blockIdx.x >> 7;
  int tid = threadIdx.x, lane = tid & 63, wid = tid >> 6;
  int g = lane >> 4, lr = lane & 15;
  const __bf16* kb = kT + (size_t)bh * DH_ * S_;
  const __bf16* vb = vT + (size_t)bh * DH_ * S_;

  f32x4 acc[4][4] = {};

  int sbeg = half * (S_ / 2);
  for (int sc0 = sbeg; sc0 < sbeg + S_ / 2; sc0 += 256) {
#pragma unroll
    for (int it = 0; it < 8; ++it) {
      int seg = tid + it * 256;
      int row = seg >> 5, col = (seg & 31) * 8;
      gload_lds16(kb + (size_t)row * S_ + sc0 + col, (void*)(kbuf + seg * 8));
      gload_lds16(vb + (size_t)row * S_ + sc0 + col, (void*)(vbuf + seg * 8));
    }
    __syncthreads();
    int sl = wid * 64;   // each wave owns a 64-wide K slice of the chunk
#pragma unroll
    for (int kk = 0; kk < 64; kk += 32) {
      bf16x8 fa[4], fb[4];
#pragma unroll
      for (int m = 0; m < 4; ++m)
        fa[m] = *(const bf16x8*)(vbuf + (m * 16 + lr) * 256 + sl + kk + g * 8);
#pragma unroll
      for (int n = 0; n < 4; ++n)
        fb[n] = *(const bf16x8*)(kbuf + (n * 16 + lr) * 256 + sl + kk + g * 8);
#pragma unroll
      for (int m = 0; m < 4; ++m)
#pragma unroll
        for (int n = 0; n < 4; ++n)
          acc[m][n] = __builtin_amdgcn_mfma_f32_16x16x32_bf16(fa[m], fb[n], acc[m][n], 0, 0, 0);
    }
    __syncthreads();
  }

  // cross-wave reduce through LDS (reuse staging space)
  float* red = (float*)smem;   // 4 x [64][64] fp32 = 64KB
#pragma unroll
  for (int m = 0; m < 4; ++m)
#pragma unroll
    for (int n = 0; n < 4; ++n)
#pragma unroll
      for (int j = 0; j < 4; ++j)
        red[wid * 4096 + (m * 16 + g * 4 + j) * 64 + n * 16 + lr] = acc[m][n][j];
  __syncthreads();
  for (int idx = tid; idx < 4096; idx += 256) {
    float s = red[idx] + red[4096 + idx] + red[8192 + idx] + red[12288 + idx];
    vkp[(size_t)(half * 128 + bh) * 4096 + idx] = s;
  }
}

// ------- ctx phase: out[b,s,h*64+d] = sum_e q[s,e]*vk[d,e] -------
// vk materialized inline from the two f32 partial halves (fused vk_reduce).
__global__ __launch_bounds__(256) void ctx_gemm(const __bf16* __restrict__ qn,
                                                const float* __restrict__ vkp,
                                                float* __restrict__ out) {
  __shared__ __align__(16) __bf16 qbuf[128 * 64];
  __shared__ __align__(16) __bf16 wbuf[64 * 64];

  int st = blockIdx.x;   // s-tile (16)
  int bh = blockIdx.y;   // 128
  int b = bh >> 4, h = bh & 15;
  int tid = threadIdx.x, lane = tid & 63, wid = tid >> 6;
  int g = lane >> 4, lr = lane & 15;
  int s0 = st * 128;

#pragma unroll
  for (int it = 0; it < 4; ++it) {
    int seg = tid + it * 256;
    int row = seg >> 3, col = (seg & 7) * 8;
    gload_lds16(qn + (size_t)(b * S_ + s0 + row) * HID_ + h * DH_ + col,
                (void*)(qbuf + seg * 8));
  }
  // fused vk reduce: wbuf[i] = bf16(vkp[bh][i] + vkp[128+bh][i])
  {
    const float* p0 = vkp + (size_t)bh * 4096;
    const float* p1 = p0 + 524288;   // half-1 partials (128*4096)
#pragma unroll
    for (int it = 0; it < 2; ++it) {
      int i = tid * 8 + it * 2048;
      f32x4 a0 = *(const f32x4*)(p0 + i);
      f32x4 a1 = *(const f32x4*)(p0 + i + 4);
      f32x4 c0 = *(const f32x4*)(p1 + i);
      f32x4 c1 = *(const f32x4*)(p1 + i + 4);
      bf16x8 v;
#pragma unroll
      for (int j = 0; j < 4; ++j) {
        v[j]     = (__bf16)(a0[j] + c0[j]);
        v[4 + j] = (__bf16)(a1[j] + c1[j]);
      }
      *(bf16x8*)(wbuf + i) = v;
    }
  }
  __syncthreads();

  f32x4 acc[2][4] = {};
#pragma unroll
  for (int kk = 0; kk < 64; kk += 32) {
    bf16x8 fa[2], fb[4];
#pragma unroll
    for (int m = 0; m < 2; ++m)
      fa[m] = *(const bf16x8*)(qbuf + (wid * 32 + m * 16 + lr) * 64 + kk + g * 8);
#pragma unroll
    for (int n = 0; n < 4; ++n)
      fb[n] = *(const bf16x8*)(wbuf + (n * 16 + lr) * 64 + kk + g * 8);
#pragma unroll
    for (int m = 0; m < 2; ++m)
#pragma unroll
      for (int n = 0; n < 4; ++n)
        acc[m][n] = __builtin_amdgcn_mfma_f32_16x16x32_bf16(fa[m], fb[n], acc[m][n], 0, 0, 0);
  }

#pragma unroll
  for (int m = 0; m < 2; ++m) {
    int rbase = s0 + wid * 32 + m * 16 + g * 4;
#pragma unroll
    for (int n = 0; n < 4; ++n) {
      int d = n * 16 + lr;
#pragma unroll
      for (int j = 0; j < 4; ++j)
        out[(size_t)(b * S_ + rbase + j) * HID_ + h * DH_ + d] = acc[m][n][j];
    }
  }
}

extern "C" void kernel_launch(void* const* d_in, const int* in_sizes, int n_in,
                              void* d_out, int out_size, void* d_ws, size_t ws_size,
                              hipStream_t stream) {
  const float* hs   = (const float*)d_in[0];
  const int*   mask = (const int*)d_in[1];
  const float* Wq   = (const float*)d_in[2];
  const float* bq   = (const float*)d_in[3];
  const float* Wk   = (const float*)d_in[4];
  const float* bk   = (const float*)d_in[5];
  const float* Wv   = (const float*)d_in[6];
  const float* bv   = (const float*)d_in[7];
  float* out = (float*)d_out;

  // ws layout (bytes): ~143.7 MB total
  char* ws = (char*)d_ws;
  __bf16* hsb    = (__bf16*)(ws);                           // 32 MB
  __bf16* Wt     = (__bf16*)(ws + (33554432));              // 6 MB
  __bf16* qn     = (__bf16*)(ws + (41943040));              // 32 MB
  __bf16* kT     = (__bf16*)(ws + (75497472));              // 32 MB
  __bf16* vT     = (__bf16*)(ws + (109051904));             // 32 MB
  float*  validf = (float*)(ws + (143654912));              // 64 KB
  float*  counts = (float*)(ws + (143654912) + 65536);      // 32 B
  // vkp (4 MB f32 partials) reuses Wt's slot: Wt is dead after qkv_gemm8.
  float*  vkp    = (float*)(ws + (33554432));

  prep<<<5128, 256, 0, stream>>>(hs, hsb, Wq, Wk, Wv, Wt, mask, validf, counts);
  qkv_gemm8<<<768, 512, 0, stream>>>(hsb, Wt, bq, bk, bv, validf, counts, qn, kT, vT);
  kv_gemm<<<256, 256, 0, stream>>>(kT, vT, vkp);
  ctx_gemm<<<dim3(16, 128), 256, 0, stream>>>(qn, vkp, out);
}

// Round 15
// 176.389 us; speedup vs baseline: 1.1974x; 1.1974x over previous
//
#include <hip/hip_runtime.h>
#include <stdint.h>

// Problem constants
#define B_    8
#define S_    2048
#define HID_  1024
#define H_    16
#define DH_   64
#define M_    (B_ * S_)   // 16384 rows

using bf16x8 = __attribute__((ext_vector_type(8))) __bf16;
using bf16x4 = __attribute__((ext_vector_type(4))) __bf16;
using f32x4  = __attribute__((ext_vector_type(4))) float;

__device__ __forceinline__ void gload_lds16(const void* g, void* l) {
  __builtin_amdgcn_global_load_lds(
      (const __attribute__((address_space(1))) void*)g,
      (__attribute__((address_space(3))) void*)l, 16, 0, 0);
}

// ---------------- fused prep: cast (blocks 0..2047), W-transpose (2048..5119),
// ---------------- mask (5120..5127) -- one launch instead of three ----------
__global__ __launch_bounds__(256) void prep(
    const float* __restrict__ hs, __bf16* __restrict__ hsb,
    const float* __restrict__ Wq, const float* __restrict__ Wk,
    const float* __restrict__ Wv, __bf16* __restrict__ Wt,
    const int* __restrict__ mask, float* __restrict__ validf,
    float* __restrict__ counts) {
  int bid = blockIdx.x;
  int tid = threadIdx.x;
  if (bid < 2048) {
    // cast hidden_states fp32 -> bf16, 8 elems/thread/iter
    int n8 = (B_ * S_ * HID_) / 8;
    int i = bid * 256 + tid;
    int stride = 2048 * 256;
    for (; i < n8; i += stride) {
      const float4* p = (const float4*)(hs + (size_t)i * 8);
      float4 a = p[0], c = p[1];
      bf16x8 v;
      v[0] = (__bf16)a.x; v[1] = (__bf16)a.y; v[2] = (__bf16)a.z; v[3] = (__bf16)a.w;
      v[4] = (__bf16)c.x; v[5] = (__bf16)c.y; v[6] = (__bf16)c.z; v[7] = (__bf16)c.w;
      *(bf16x8*)(hsb + (size_t)i * 8) = v;
    }
  } else if (bid < 5120) {
    // W [k][n] -> Wt [w][n][k] bf16
    __shared__ float tile[32][33];
    int idx = bid - 2048;
    int w = idx >> 10, r = idx & 1023;
    int k0 = (r & 31) * 32, n0 = (r >> 5) * 32;
    const float* W = (w == 0) ? Wq : (w == 1) ? Wk : Wv;
    int tx = tid & 31, ty = tid >> 5;
#pragma unroll
    for (int i = 0; i < 4; ++i)
      tile[ty * 4 + i][tx] = W[(size_t)(k0 + ty * 4 + i) * HID_ + n0 + tx];
    __syncthreads();
#pragma unroll
    for (int i = 0; i < 4; ++i)
      Wt[(size_t)w * HID_ * HID_ + (size_t)(n0 + ty * 4 + i) * HID_ + k0 + tx] =
          (__bf16)tile[tx][ty * 4 + i];
  } else {
    // per-row validity + per-batch count
    __shared__ float red[256];
    int b = bid - 5120;
    float cnt = 0.f;
    for (int s = tid; s < S_; s += 256) {
      float v = (mask[b * S_ + s] == 0) ? 1.f : 0.f;
      validf[b * S_ + s] = v;
      cnt += v;
    }
    red[tid] = cnt;
    __syncthreads();
    for (int off = 128; off > 0; off >>= 1) {
      if (tid < off) red[tid] += red[tid + off];
      __syncthreads();
    }
    if (tid == 0) counts[b] = red[0];
  }
}

// ============ QKV GEMM: 256x256 tile, BK=64, 8-wave, pipelined K-step =======
// (exact R3 structure -- best measured across NINE variants: 124us,
//  MfmaUtil 35%, 0 bank conflicts, FETCH 94.6MB)
// One vmcnt(0)+s_barrier per K-step; ds_reads front-loaded in pinned groups;
// MFMA clusters guarded by counted lgkmcnt so waves drift within a step and
// LDS reads overlap MFMA across waves. T2 XOR-swizzle, T5 setprio.
// Measured variant map: R2(8-phase barriers)=154, R3(this)=124, R4(2-gate
// counted vmcnt)=135, R8(B-from-global)=172, R10(128x128/wave)=360 spill,
// R11(lookahead 8-phase)=153, R12(2 blocks/CU)=137, R14(32x32 mfma)=162
// 4-way bank conflicts (128B row stride => bank = f(col-slot) only; 32
// rows/slot irreducible below 4-way with 3-bit slot swizzle).
// Family floor: serialized per-CU LDS-issue + MFMA ~= 6200 cyc/step.
__global__ __launch_bounds__(512, 2) void qkv_gemm8(
    const __bf16* __restrict__ hsb, const __bf16* __restrict__ Wt,
    const float* __restrict__ biasq, const float* __restrict__ biask,
    const float* __restrict__ biasv, const float* __restrict__ validf,
    const float* __restrict__ counts, __bf16* __restrict__ qn,
    __bf16* __restrict__ kT, __bf16* __restrict__ vT) {
  __shared__ __bf16 As[2][2][128 * 64];   // [dbuf][m-half][row*64+col]
  __shared__ __bf16 Bs[2][2][128 * 64];   // [dbuf][n-half][row*64+col]

  // XCD-aware block order: each XCD gets 8 consecutive tm x all 12 (tn,w).
  int bid = blockIdx.x;
  int swz = (bid & 7) * 96 + (bid >> 3);       // 768 % 8 == 0 -> bijective
  int tm = swz / 12;
  int tnw = swz - tm * 12;
  int tn = tnw & 3;
  int w  = tnw >> 2;

  int tid = threadIdx.x;
  int lane = tid & 63, wid = tid >> 6;
  int lr = lane & 15, g = lane >> 4;
  int wr = wid >> 2, wcn = wid & 3;

  int m0 = tm * 256, n0 = tn * 256;
  const __bf16* Bsrc = Wt + (size_t)w * (HID_ * HID_);

  // staging constants (512 threads stage one 128x64 half = 2 x 16B each)
  int srow = tid >> 3;                              // row 0..63 (+64 for seg 1)
  int scol = ((tid & 7) ^ (srow & 7)) << 3;         // swizzled source col (elems)
  int soff = tid * 16;                              // LDS byte offset (+8192 seg 1)

  auto stA = [&](int t_, int ah) {
    const __bf16* s0 = hsb + (size_t)(m0 + ah * 128 + srow) * HID_ + t_ * 64 + scol;
    char* d = (char*)&As[t_ & 1][ah][0] + soff;
    gload_lds16(s0, d);
    gload_lds16(s0 + (size_t)64 * HID_, d + 8192);
  };
  auto stB = [&](int t_, int bh) {
    const __bf16* s0 = Bsrc + (size_t)(n0 + bh * 128 + srow) * HID_ + t_ * 64 + scol;
    char* d = (char*)&Bs[t_ & 1][bh][0] + soff;
    gload_lds16(s0, d);
    gload_lds16(s0 + (size_t)64 * HID_, d + 8192);
  };

  // ds_read constants
  int swz8 = (lr & 7) << 4;
  int arow = wr * 64 + lr;          // + mf*16
  int brow = (wcn & 1) * 64 + lr;   // + nf*16
  int bsel = wcn >> 1;

  f32x4 acc[8][4] = {};
  bf16x8 fb[4], fbN[4], fa0[4], fa1[4];

#define RD_A(DST, BUF, MH, KK)                                                \
  _Pragma("unroll")                                                           \
  for (int mf = 0; mf < 4; ++mf)                                              \
    DST[mf] = *(const bf16x8*)((const char*)&As[BUF][MH][0] +                 \
                               (arow + mf * 16) * 128 +                       \
                               (((KK) * 64 + g * 16) ^ swz8));                \
  __builtin_amdgcn_sched_barrier(0);

#define RD_B(DST, BUF, KK)                                                    \
  _Pragma("unroll")                                                           \
  for (int nf = 0; nf < 4; ++nf)                                              \
    DST[nf] = *(const bf16x8*)((const char*)&Bs[BUF][bsel][0] +               \
                               (brow + nf * 16) * 128 +                       \
                               (((KK) * 64 + g * 16) ^ swz8));                \
  __builtin_amdgcn_sched_barrier(0);

#define CLUSTER(ACCB, FA, FB, LG)                                             \
  asm volatile("s_waitcnt lgkmcnt(" #LG ")" ::: "memory");                    \
  __builtin_amdgcn_sched_barrier(0);                                          \
  __builtin_amdgcn_s_setprio(1);                                              \
  _Pragma("unroll")                                                           \
  for (int mf = 0; mf < 4; ++mf)                                              \
    _Pragma("unroll")                                                         \
    for (int nf = 0; nf < 4; ++nf)                                            \
      acc[(ACCB) + mf][nf] = __builtin_amdgcn_mfma_f32_16x16x32_bf16(         \
          FA[mf], FB[nf], acc[(ACCB) + mf][nf], 0, 0, 0);                     \
  __builtin_amdgcn_s_setprio(0);                                              \
  __builtin_amdgcn_sched_barrier(0);

  // prologue: stage tile 0 into buf 0
  stA(0, 0); stA(0, 1); stB(0, 0); stB(0, 1);

#pragma unroll 2
  for (int t = 0; t < 16; ++t) {
    int buf = t & 1;
    // tile t staged (issued during t-1); all reads of t-1 complete.
    asm volatile("s_waitcnt vmcnt(0)" ::: "memory");
    __builtin_amdgcn_s_barrier();
    __builtin_amdgcn_sched_barrier(0);

    // front-loaded reads, pinned group order (12 outstanding after this):
    RD_B(fb,  buf, 0);        // G1: oldest 4
    RD_A(fa0, buf, 0, 0);     // G2
    RD_A(fa1, buf, 1, 0);     // G3
    if (t < 15) { stA(t + 1, 0); stA(t + 1, 1); }

    CLUSTER(0, fa0, fb, 4)    // needs G1,G2 (8 oldest) -> lgkm(4)

    RD_B(fbN, buf, 1);        // G4
    RD_A(fa0, buf, 0, 1);     // G5 (reuse fa0 regs)
    if (t < 15) stB(t + 1, 0);

    CLUSTER(4, fa1, fb, 8)    // needs G3 done; G4,G5 outstanding -> lgkm(8)

    RD_A(fa1, buf, 1, 1);     // G6 (reuse fa1 regs)
    if (t < 15) stB(t + 1, 1);

    CLUSTER(0, fa0, fbN, 4)   // needs G4,G5; G6 outstanding -> lgkm(4)
    CLUSTER(4, fa1, fbN, 0)   // needs G6 -> lgkm(0)
  }
#undef RD_A
#undef RD_B
#undef CLUSTER

  // ---- fused epilogue ----
  const float* bias = (w == 0) ? biasq : (w == 1) ? biask : biasv;
  float bb[4];
#pragma unroll
  for (int nf = 0; nf < 4; ++nf) bb[nf] = bias[n0 + wcn * 64 + nf * 16 + lr];

  int batch = m0 >> 11;              // 256-row tile never crosses batch (2048 rows)
  float invcnt = 1.0f / counts[batch];
  int h = tn * 4 + wcn;              // head owned by this wave

#pragma unroll
  for (int m = 0; m < 8; ++m) {
    int mh = m >> 2, mf = m & 3;
    int rbase = m0 + mh * 128 + wr * 64 + mf * 16 + g * 4;
    float vld[4];
#pragma unroll
    for (int j = 0; j < 4; ++j) vld[j] = validf[rbase + j];
    float ss[4] = {0.f, 0.f, 0.f, 0.f};
#pragma unroll
    for (int nf = 0; nf < 4; ++nf)
#pragma unroll
      for (int j = 0; j < 4; ++j) {
        float x = (acc[m][nf][j] + bb[nf]) * vld[j];
        acc[m][nf][j] = x;
        ss[j] += x * x;
      }
    float sc[4];
#pragma unroll
    for (int j = 0; j < 4; ++j) {
      float s = ss[j];
      s += __shfl_xor(s, 1);
      s += __shfl_xor(s, 2);
      s += __shfl_xor(s, 4);
      s += __shfl_xor(s, 8);   // reduce over 16 lanes holding this row's 64 cols
      if (w == 2) sc[j] = vld[j] * invcnt;
      else        sc[j] = 1.0f / fmaxf(sqrtf(s), 1e-12f);
    }
    if (w == 0) {
#pragma unroll
      for (int nf = 0; nf < 4; ++nf) {
        int c = n0 + wcn * 64 + nf * 16 + lr;
#pragma unroll
        for (int j = 0; j < 4; ++j)
          qn[(size_t)(rbase + j) * HID_ + c] = (__bf16)(acc[m][nf][j] * sc[j]);
      }
    } else {
      __bf16* dst = (w == 1) ? kT : vT;
      int sbase = rbase & (S_ - 1);
#pragma unroll
      for (int nf = 0; nf < 4; ++nf) {
        int d = nf * 16 + lr;
        bf16x4 pk;
#pragma unroll
        for (int j = 0; j < 4; ++j) pk[j] = (__bf16)(acc[m][nf][j] * sc[j]);
        *(bf16x4*)(dst + (size_t)((batch * H_ + h) * DH_ + d) * S_ + sbase) = pk;
      }
    }
  }
}

// ---- kv phase: vkp[half][bh][d][e] = sum_{s in half} v[s,d]*k[s,e] ----
// 256 blocks (full GPU); f32 partials, reduced inside ctx_gemm.
__global__ __launch_bounds__(256) void kv_gemm(const __bf16* __restrict__ kT,
                                               const __bf16* __restrict__ vT,
                                               float* __restrict__ vkp) {
  __shared__ __align__(16) char smem[65536];
  __bf16* kbuf = (__bf16*)smem;              // [64][256]
  __bf16* vbuf = (__bf16*)(smem + 32768);    // [64][256]

  int bh = blockIdx.x & 127, half = blockIdx.x >> 7;
  int tid = threadIdx.x, lane = tid & 63, wid = tid >> 6;
  int g = lane >> 4, lr = lane & 15;
  const __bf16* kb = kT + (size_t)bh * DH_ * S_;
  const __bf16* vb = vT + (size_t)bh * DH_ * S_;

  f32x4 acc[4][4] = {};

  int sbeg = half * (S_ / 2);
  for (int sc0 = sbeg; sc0 < sbeg + S_ / 2; sc0 += 256) {
#pragma unroll
    for (int it = 0; it < 8; ++it) {
      int seg = tid + it * 256;
      int row = seg >> 5, col = (seg & 31) * 8;
      gload_lds16(kb + (size_t)row * S_ + sc0 + col, (void*)(kbuf + seg * 8));
      gload_lds16(vb + (size_t)row * S_ + sc0 + col, (void*)(vbuf + seg * 8));
    }
    __syncthreads();
    int sl = wid * 64;   // each wave owns a 64-wide K slice of the chunk
#pragma unroll
    for (int kk = 0; kk < 64; kk += 32) {
      bf16x8 fa[4], fb[4];
#pragma unroll
      for (int m = 0; m < 4; ++m)
        fa[m] = *(const bf16x8*)(vbuf + (m * 16 + lr) * 256 + sl + kk + g * 8);
#pragma unroll
      for (int n = 0; n < 4; ++n)
        fb[n] = *(const bf16x8*)(kbuf + (n * 16 + lr) * 256 + sl + kk + g * 8);
#pragma unroll
      for (int m = 0; m < 4; ++m)
#pragma unroll
        for (int n = 0; n < 4; ++n)
          acc[m][n] = __builtin_amdgcn_mfma_f32_16x16x32_bf16(fa[m], fb[n], acc[m][n], 0, 0, 0);
    }
    __syncthreads();
  }

  // cross-wave reduce through LDS (reuse staging space)
  float* red = (float*)smem;   // 4 x [64][64] fp32 = 64KB
#pragma unroll
  for (int m = 0; m < 4; ++m)
#pragma unroll
    for (int n = 0; n < 4; ++n)
#pragma unroll
      for (int j = 0; j < 4; ++j)
        red[wid * 4096 + (m * 16 + g * 4 + j) * 64 + n * 16 + lr] = acc[m][n][j];
  __syncthreads();
  for (int idx = tid; idx < 4096; idx += 256) {
    float s = red[idx] + red[4096 + idx] + red[8192 + idx] + red[12288 + idx];
    vkp[(size_t)(half * 128 + bh) * 4096 + idx] = s;
  }
}

// ------- ctx phase: out[b,s,h*64+d] = sum_e q[s,e]*vk[d,e] -------
// vk materialized inline from the two f32 partial halves (fused vk_reduce).
__global__ __launch_bounds__(256) void ctx_gemm(const __bf16* __restrict__ qn,
                                                const float* __restrict__ vkp,
                                                float* __restrict__ out) {
  __shared__ __align__(16) __bf16 qbuf[128 * 64];
  __shared__ __align__(16) __bf16 wbuf[64 * 64];

  int st = blockIdx.x;   // s-tile (16)
  int bh = blockIdx.y;   // 128
  int b = bh >> 4, h = bh & 15;
  int tid = threadIdx.x, lane = tid & 63, wid = tid >> 6;
  int g = lane >> 4, lr = lane & 15;
  int s0 = st * 128;

#pragma unroll
  for (int it = 0; it < 4; ++it) {
    int seg = tid + it * 256;
    int row = seg >> 3, col = (seg & 7) * 8;
    gload_lds16(qn + (size_t)(b * S_ + s0 + row) * HID_ + h * DH_ + col,
                (void*)(qbuf + seg * 8));
  }
  // fused vk reduce: wbuf[i] = bf16(vkp[bh][i] + vkp[128+bh][i])
  {
    const float* p0 = vkp + (size_t)bh * 4096;
    const float* p1 = p0 + 524288;   // half-1 partials (128*4096)
#pragma unroll
    for (int it = 0; it < 2; ++it) {
      int i = tid * 8 + it * 2048;
      f32x4 a0 = *(const f32x4*)(p0 + i);
      f32x4 a1 = *(const f32x4*)(p0 + i + 4);
      f32x4 c0 = *(const f32x4*)(p1 + i);
      f32x4 c1 = *(const f32x4*)(p1 + i + 4);
      bf16x8 v;
#pragma unroll
      for (int j = 0; j < 4; ++j) {
        v[j]     = (__bf16)(a0[j] + c0[j]);
        v[4 + j] = (__bf16)(a1[j] + c1[j]);
      }
      *(bf16x8*)(wbuf + i) = v;
    }
  }
  __syncthreads();

  f32x4 acc[2][4] = {};
#pragma unroll
  for (int kk = 0; kk < 64; kk += 32) {
    bf16x8 fa[2], fb[4];
#pragma unroll
    for (int m = 0; m < 2; ++m)
      fa[m] = *(const bf16x8*)(qbuf + (wid * 32 + m * 16 + lr) * 64 + kk + g * 8);
#pragma unroll
    for (int n = 0; n < 4; ++n)
      fb[n] = *(const bf16x8*)(wbuf + (n * 16 + lr) * 64 + kk + g * 8);
#pragma unroll
    for (int m = 0; m < 2; ++m)
#pragma unroll
      for (int n = 0; n < 4; ++n)
        acc[m][n] = __builtin_amdgcn_mfma_f32_16x16x32_bf16(fa[m], fb[n], acc[m][n], 0, 0, 0);
  }

#pragma unroll
  for (int m = 0; m < 2; ++m) {
    int rbase = s0 + wid * 32 + m * 16 + g * 4;
#pragma unroll
    for (int n = 0; n < 4; ++n) {
      int d = n * 16 + lr;
#pragma unroll
      for (int j = 0; j < 4; ++j)
        out[(size_t)(b * S_ + rbase + j) * HID_ + h * DH_ + d] = acc[m][n][j];
    }
  }
}

extern "C" void kernel_launch(void* const* d_in, const int* in_sizes, int n_in,
                              void* d_out, int out_size, void* d_ws, size_t ws_size,
                              hipStream_t stream) {
  const float* hs   = (const float*)d_in[0];
  const int*   mask = (const int*)d_in[1];
  const float* Wq   = (const float*)d_in[2];
  const float* bq   = (const float*)d_in[3];
  const float* Wk   = (const float*)d_in[4];
  const float* bk   = (const float*)d_in[5];
  const float* Wv   = (const float*)d_in[6];
  const float* bv   = (const float*)d_in[7];
  float* out = (float*)d_out;

  // ws layout (bytes): ~143.7 MB total
  char* ws = (char*)d_ws;
  __bf16* hsb    = (__bf16*)(ws);                           // 32 MB
  __bf16* Wt     = (__bf16*)(ws + (33554432));              // 6 MB
  __bf16* qn     = (__bf16*)(ws + (41943040));              // 32 MB
  __bf16* kT     = (__bf16*)(ws + (75497472));              // 32 MB
  __bf16* vT     = (__bf16*)(ws + (109051904));             // 32 MB
  float*  validf = (float*)(ws + (143654912));              // 64 KB
  float*  counts = (float*)(ws + (143654912) + 65536);      // 32 B
  // vkp (4 MB f32 partials) reuses Wt's slot: Wt is dead after qkv_gemm8.
  float*  vkp    = (float*)(ws + (33554432));

  prep<<<5128, 256, 0, stream>>>(hs, hsb, Wq, Wk, Wv, Wt, mask, validf, counts);
  qkv_gemm8<<<768, 512, 0, stream>>>(hsb, Wt, bq, bk, bv, validf, counts, qn, kT, vT);
  kv_gemm<<<256, 256, 0, stream>>>(kT, vT, vkp);
  ctx_gemm<<<dim3(16, 128), 256, 0, stream>>>(qn, vkp, out);
}